// Round 9
// baseline (3178.132 us; speedup 1.0000x reference)
//
#include <hip/hip_runtime.h>
#include <hip/hip_bf16.h>

// Problem constants
#define CUT0 2000
#define CUT1 20000
#define CUT2 50000
#define BSZ  8192
#define HDIM 1024
#define N0MAX 18000   // CUT1-CUT0
#define N1MAX 30000   // CUT2-CUT1
#define HEADW 2002    // CUT0 + 2 tail cols

typedef __attribute__((ext_vector_type(8))) short bf16x8;
typedef __attribute__((ext_vector_type(4))) float f32x4;
typedef __attribute__((ext_vector_type(4))) unsigned short us4;

__device__ __forceinline__ unsigned short f2bf(float x) {
    // round-to-nearest-even bf16
    unsigned u = __float_as_uint(x);
    unsigned r = u + 0x7fffu + ((u >> 16) & 1u);
    return (unsigned short)(r >> 16);
}

__device__ __forceinline__ bf16x8 pack8(f32x4 a, f32x4 b) {
    bf16x8 w;
    w[0] = (short)f2bf(a[0]); w[1] = (short)f2bf(a[1]);
    w[2] = (short)f2bf(a[2]); w[3] = (short)f2bf(a[3]);
    w[4] = (short)f2bf(b[0]); w[5] = (short)f2bf(b[1]);
    w[6] = (short)f2bf(b[2]); w[7] = (short)f2bf(b[3]);
    return w;
}

typedef const __attribute__((address_space(1))) void* gas_ptr;
typedef __attribute__((address_space(3))) void* las_ptr;

__device__ __forceinline__ void load_lds16(const void* g, void* l) {
    // 16B per lane, LDS dest = wave-uniform base + lane*16 (m97 pattern)
    __builtin_amdgcn_global_load_lds((gas_ptr)g, (las_ptr)l, 16, 0, 0);
}

// ---------------------------------------------------------------------------
// cvt_all: one launch doing every fp32->bf16 convert + bias concat + the
// cluster-index build. Segmented by blockIdx (2048 elems/block for cvt):
//   [0,1000)      embed[0:2000] -> ebf rows 0..1999
//   1000          tailW (2x1024) -> ebf rows 2000..2001
//   [1001,1513)   down0 -> d0bf
//   [1513,1641)   down1 -> d1bf
//   1641          bias2002 = [slbias; tailb] (fp32 copy)
//   1642          build_idx: idx0 (2000<=t<20000), idx1 (t>=20000), counts.
// ---------------------------------------------------------------------------
#define CVT_NBLK 1643
__global__ __launch_bounds__(256) void cvt_all(
    const float* __restrict__ embed,  const float* __restrict__ tailW,
    const float* __restrict__ down0,  const float* __restrict__ down1,
    const float* __restrict__ slbias, const float* __restrict__ tailb,
    const int* __restrict__ targets,
    unsigned short* __restrict__ ebf,
    unsigned short* __restrict__ d0bf, unsigned short* __restrict__ d1bf,
    float* __restrict__ bias2002,
    int* __restrict__ n0p, int* __restrict__ n1p,
    int* __restrict__ idx0, int* __restrict__ idx1)
{
    const int b = blockIdx.x;
    if (b == 1642) {
        // ---- build_idx ----
        __shared__ int s0[256], s1[256];
        const int t = threadIdx.x;
        const int base = t * 32;
        int tg[32];
        int c0n = 0, c1n = 0;
#pragma unroll
        for (int i = 0; i < 32; ++i) {
            tg[i] = targets[base + i];
            c0n += (tg[i] >= CUT0 && tg[i] < CUT1) ? 1 : 0;
            c1n += (tg[i] >= CUT1) ? 1 : 0;
        }
        s0[t] = c0n; s1[t] = c1n;
        __syncthreads();
        for (int o = 1; o < 256; o <<= 1) {
            int v0 = 0, v1 = 0;
            if (t >= o) { v0 = s0[t - o]; v1 = s1[t - o]; }
            __syncthreads();
            s0[t] += v0; s1[t] += v1;
            __syncthreads();
        }
        int p0 = s0[t] - c0n, p1 = s1[t] - c1n;   // exclusive prefix
#pragma unroll
        for (int i = 0; i < 32; ++i) {
            if (tg[i] >= CUT0 && tg[i] < CUT1)      idx0[p0++] = base + i;
            else if (tg[i] >= CUT1)                 idx1[p1++] = base + i;
        }
        if (t == 255) { *n0p = s0[255]; *n1p = s1[255]; }
        return;
    }
    if (b == 1641) {
        for (int j = threadIdx.x; j < HEADW; j += 256)
            bias2002[j] = (j < CUT0) ? slbias[j] : tailb[j - CUT0];
        return;
    }
    const float* src; unsigned short* dst; long long e;
    if (b < 1000)      { src = embed; dst = ebf;  e = (long long)b * 2048; }
    else if (b == 1000){ src = tailW; dst = ebf + (size_t)CUT0 * HDIM; e = 0; }
    else if (b < 1513) { src = down0; dst = d0bf; e = (long long)(b - 1001) * 2048; }
    else               { src = down1; dst = d1bf; e = (long long)(b - 1513) * 2048; }
    const long long i = e + (long long)threadIdx.x * 8;
    f32x4 a = *(const f32x4*)(src + i);
    f32x4 c = *(const f32x4*)(src + i + 4);
    us4 p = { f2bf(a[0]), f2bf(a[1]), f2bf(a[2]), f2bf(a[3]) };
    us4 q = { f2bf(c[0]), f2bf(c[1]), f2bf(c[2]), f2bf(c[3]) };
    *(us4*)(dst + i)     = p;
    *(us4*)(dst + i + 4) = q;
}

// ---------------------------------------------------------------------------
// gemm_body: C[m,n] = sum_k A[m,k]*B[n,k] (+bias[n]).  (R4..R8-verified core.)
//   256x256 tile, BK=32, 512 threads = 8 waves (2M x 4N), 128x64 per wave.
//   RING-slot LDS (RING=4: 128 KiB/1 block/CU; RING=2: 64 KiB/2 blocks/CU),
//   RING-1 tiles prefetched ahead, counted vmcnt = 4*infl, raw s_barrier,
//   T5 setprio. Ring safety (RING=2): slot (t+1)&1's readers (tile t-1)
//   finish at iter t-1's end barrier, strictly before iter t's issue.
//   Bank swizzle: rows are 64B so the involution is slot ^ ((row>>1)&3),
//   applied on gload_lds SOURCE pre-swizzle, A_F32 ds_write, and ds_read
//   (rule #21: both-sides-or-neither).
//   A_F32 (RING=4 only): A read fp32, in-register cvt, T14 split; A-reg
//   loads issued BEFORE issueB (R8: keeps implicit ds_write wait at
//   vmcnt(2), not 0). Manual ladder (8,4,2,0); implicit waits dominate.
//   Rows clamped to M-1/N-1 (don't-care values, epilogue guards).
//   LDS is DECLARED BY THE CALLER and passed in (R6 lesson: hipcc SUMS
//   function-scope __shared__ across inlined template instantiations).
//   (R3 lesson: do NOT 1D/XCD-swizzle grids that early-exit on device M.)
//   (R8 lesson: do NOT permute role-merged grids -- scatters L2 panel reuse.)
// ---------------------------------------------------------------------------
template<int RING, bool A_F32, bool SPLIT_GATHER, bool OUT_BF16, bool HAS_BIAS>
__device__ __forceinline__ void gemm_body(
    unsigned short (* __restrict__ As)[8192],   // [RING][8192] caller LDS
    unsigned short (* __restrict__ Bs)[8192],   // [RING][8192] caller LDS
    const void* __restrict__ Av, const float* __restrict__ AgF,
    const unsigned short* __restrict__ B,
    int gsplit, int gbase, const int* __restrict__ idxTail,
    int M, int N, int K,
    const float* __restrict__ bias,
    void* __restrict__ Cv, long long cbase, int ldC,
    int m0, int n0)
{
    static_assert(RING == 2 || RING == 4, "ring size");
    constexpr int PF = RING - 1;          // tiles prefetched ahead
    constexpr int SMSK = RING - 1;        // slot mask

    const int tid  = threadIdx.x;
    const int wave = tid >> 6, lane = tid & 63;
    const int wr = wave >> 2;        // 0..1  (M)
    const int wc = wave & 3;         // 0..3  (N)
    const int lrow = lane & 15;
    const int quad = lane >> 4;

    // ---- B staging (gload_lds, pre-swizzled global source; rule #21)
    const int srow = lane >> 2;                                  // 0..15
    const int scol = (((lane & 3) ^ ((srow >> 1) & 3)) << 3);    // elems
    int tr0 = wave * 32 + srow, tr1 = tr0 + 16;
    int bn0 = n0 + tr0; bn0 = bn0 < N ? bn0 : N - 1;
    int bn1 = n0 + tr1; bn1 = bn1 < N ? bn1 : N - 1;
    const unsigned short* bP0 = B + (long long)bn0 * K + scol;
    const unsigned short* bP1 = B + (long long)bn1 * K + scol;

    // ---- A staging setup
    const unsigned short* aP0 = nullptr;
    const unsigned short* aP1 = nullptr;
    const float* aF = nullptr;
    int oA0 = 0, oA1 = 0, sA0 = 0, sA1 = 0;
    if constexpr (!A_F32) {
        int am0 = m0 + tr0; am0 = am0 < M ? am0 : M - 1;
        int am1 = m0 + tr1; am1 = am1 < M ? am1 : M - 1;
        long long ar0, ar1;
        if constexpr (SPLIT_GATHER) {
            ar0 = (am0 < gsplit) ? (long long)(gbase + am0) : (long long)idxTail[am0 - gsplit];
            ar1 = (am1 < gsplit) ? (long long)(gbase + am1) : (long long)idxTail[am1 - gsplit];
        } else { ar0 = am0; ar1 = am1; }
        const unsigned short* Ab = (const unsigned short*)Av;
        aP0 = Ab + ar0 * (long long)K + scol;
        aP1 = Ab + ar1 * (long long)K + scol;
    } else {
        // lane l -> row rA=l>>1 (2 lanes/row); slots sA0=l&1, sA1=2+(l&1);
        // write at LDS col (s ^ ((rA>>1)&3)): enumerated 2-way max (free)
        const int rA  = lane >> 1;                // 0..31
        const int trA = wave * 32 + rA;           // LDS row 0..255
        int amF = m0 + trA; amF = amF < M ? amF : M - 1;
        long long rowi; const float* bp;
        if constexpr (SPLIT_GATHER) {
            if (amF < gsplit) { rowi = (long long)(gbase + amF); bp = (const float*)Av; }
            else              { rowi = (long long)idxTail[amF - gsplit]; bp = AgF; }
        } else { rowi = amF; bp = (const float*)Av; }
        aF  = bp + rowi * (long long)K;
        sA0 = (lane & 1);
        sA1 = 2 + (lane & 1);
        const int xA = (rA >> 1) & 3;
        oA0 = trA * 32 + ((sA0 ^ xA) << 3);
        oA1 = trA * 32 + ((sA1 ^ xA) << 3);
    }

    f32x4 acc[8][4];
#pragma unroll
    for (int i = 0; i < 8; ++i)
#pragma unroll
        for (int j = 0; j < 4; ++j) acc[i][j] = (f32x4){0.f, 0.f, 0.f, 0.f};

    const int KT = K >> 5;   // BK = 32

    auto issueB = [&](int tt) {
        unsigned short* bs = &Bs[tt & SMSK][wave * 1024];
        load_lds16(bP0 + (tt << 5), bs);
        load_lds16(bP1 + (tt << 5), bs + 512);
    };
    auto issueA16 = [&](int tt) {
        unsigned short* as = &As[tt & SMSK][wave * 1024];
        load_lds16(aP0 + (tt << 5), as);
        load_lds16(aP1 + (tt << 5), as + 512);
    };

    // prologue: PF tiles in flight (A_F32: A staged immediately, B via ring)
    const int npro = KT < PF ? KT : PF;
    for (int tt = 0; tt < npro; ++tt) {
        if constexpr (!A_F32) {
            issueB(tt);
            issueA16(tt);
        } else {
            const float* p = aF + (tt << 5);
            f32x4 x0 = *(const f32x4*)(p + sA0 * 8);
            f32x4 x1 = *(const f32x4*)(p + sA0 * 8 + 4);
            f32x4 y0 = *(const f32x4*)(p + sA1 * 8);
            f32x4 y1 = *(const f32x4*)(p + sA1 * 8 + 4);
            issueB(tt);                      // B newer than A-regs (R8)
            *(bf16x8*)&As[tt & SMSK][oA0] = pack8(x0, x1);
            *(bf16x8*)&As[tt & SMSK][oA1] = pack8(y0, y1);
        }
    }
    if constexpr (A_F32)
        asm volatile("s_waitcnt lgkmcnt(0)" ::: "memory");

    // read swizzle: global slot quad lives at LDS slot quad^((R>>1)&3);
    // (R>>1)&3 == (lrow>>1)&3 (R = 16*sub + lrow). Per-lane constant.
    const int rdswz = ((quad ^ ((lrow >> 1) & 3)) << 3);     // elems

    for (int t = 0; t < KT; ++t) {
        const int tt = t + PF;
        const bool pf = (tt < KT);

        f32x4 x0, x1, y0, y1;                    // A_F32 in-flight A regs (T14)
        if constexpr (!A_F32) {
            if (pf) { issueB(tt); issueA16(tt); }
        } else {
            if (pf) {
                // A-regs FIRST (older queue slots), then B (R8): the
                // post-MFMA ds_write's implicit wait is then vmcnt(2), not 0.
                const float* p = aF + (tt << 5);
                x0 = *(const f32x4*)(p + sA0 * 8);
                x1 = *(const f32x4*)(p + sA0 * 8 + 4);
                y0 = *(const f32x4*)(p + sA1 * 8);
                y1 = *(const f32x4*)(p + sA1 * 8 + 4);
                issueB(tt);
            }
        }

        int infl = KT - 1 - t; if (infl > PF) infl = PF;    // tiles beyond t in flight
        if constexpr (!A_F32) {
            // counted vmcnt = 4 * infl (4 gloads per in-flight tile)
            if (infl >= 3)      asm volatile("s_waitcnt vmcnt(12)" ::: "memory");
            else if (infl == 2) asm volatile("s_waitcnt vmcnt(8)"  ::: "memory");
            else if (infl == 1) asm volatile("s_waitcnt vmcnt(4)"  ::: "memory");
            else                asm volatile("s_waitcnt vmcnt(0)"  ::: "memory");
        } else {
            if (infl >= 3)      asm volatile("s_waitcnt vmcnt(8)"  ::: "memory");
            else if (infl == 2) asm volatile("s_waitcnt vmcnt(4)"  ::: "memory");
            else if (infl == 1) asm volatile("s_waitcnt vmcnt(2)"  ::: "memory");
            else                asm volatile("s_waitcnt vmcnt(0)"  ::: "memory");
        }

        __builtin_amdgcn_s_barrier();
        asm volatile("" ::: "memory");   // keep ds_reads below the barrier

        const unsigned short* Asl = &As[t & SMSK][0];
        const unsigned short* Bsl = &Bs[t & SMSK][0];

        bf16x8 a[8], b[4];
#pragma unroll
        for (int mi = 0; mi < 8; ++mi) {
            const int R = wr * 128 + mi * 16 + lrow;
            a[mi] = *(const bf16x8*)&Asl[R * 32 + rdswz];
        }
#pragma unroll
        for (int nj = 0; nj < 4; ++nj) {
            const int R = wc * 64 + nj * 16 + lrow;
            b[nj] = *(const bf16x8*)&Bsl[R * 32 + rdswz];
        }

        __builtin_amdgcn_s_setprio(1);
#pragma unroll
        for (int mi = 0; mi < 8; ++mi)
#pragma unroll
            for (int nj = 0; nj < 4; ++nj)
                acc[mi][nj] = __builtin_amdgcn_mfma_f32_16x16x32_bf16(
                    a[mi], b[nj], acc[mi][nj], 0, 0, 0);
        __builtin_amdgcn_s_setprio(0);

        if constexpr (A_F32) {
            // deferred cvt + swizzled ds_write for tile t+PF (slot freed at
            // end of iter t-1; readers wait >=2 barriers from here).
            if (pf) {
                *(bf16x8*)&As[tt & SMSK][oA0] = pack8(x0, x1);
                *(bf16x8*)&As[tt & SMSK][oA1] = pack8(y0, y1);
            }
            asm volatile("s_waitcnt lgkmcnt(0)" ::: "memory");
        }

        asm volatile("" ::: "memory");   // keep ds ops above the end barrier
        __builtin_amdgcn_s_barrier();    // slot t&SMSK free for tile t+RING
    }

    // epilogue: C/D layout col=lane&15, row=quad*4+reg  [m89/m91 verified]
#pragma unroll
    for (int mi = 0; mi < 8; ++mi) {
#pragma unroll
        for (int v = 0; v < 4; ++v) {
            int m = m0 + wr * 128 + mi * 16 + quad * 4 + v;
            if (m >= M) continue;
#pragma unroll
            for (int nj = 0; nj < 4; ++nj) {
                int n = n0 + wc * 64 + nj * 16 + lrow;
                if (n >= N) continue;
                float r = acc[mi][nj][v];
                if constexpr (OUT_BF16) {
                    ((unsigned short*)Cv)[(long long)m * ldC + n] = f2bf(r);
                } else {
                    if constexpr (HAS_BIAS) r += bias[n];
                    ((float*)Cv)[cbase + (long long)m * ldC + n] = r;
                }
            }
        }
    }
}

// ---------------------------------------------------------------------------
// gemm_mid: head + c0 + c1 in one launch (1D grid, 818 blocks, role by id).
//   [0,256)    head: out[:, 0:2002] = hidden @ [embed0;tailW]^T + bias2002
//   [256,668)  c0 = [embed[2000:20000]; hidden[idx0]] @ down0^T -> bf16
//   [668,818)  c1 = [embed[20000:50000]; hidden[idx1]] @ down1^T -> bf16
// Contiguous role slabs (R8 lesson: permuting ids scatters L2 panel reuse).
// Ring-4, single 128 KiB LDS slab shared by all instantiations (R6 fix).
// ---------------------------------------------------------------------------
__global__ __launch_bounds__(512) void gemm_mid(
    const float* __restrict__ hidden, const float* __restrict__ embed,
    const unsigned short* __restrict__ ebf,
    const unsigned short* __restrict__ d0bf, const unsigned short* __restrict__ d1bf,
    const float* __restrict__ bias2002,
    const int* __restrict__ idx0, const int* __restrict__ idx1,
    const int* __restrict__ n0p, const int* __restrict__ n1p,
    float* __restrict__ out,
    unsigned short* __restrict__ c0, unsigned short* __restrict__ c1)
{
    __shared__ unsigned short As[4][8192];
    __shared__ unsigned short Bs[4][8192];
    int id = blockIdx.x;
    if (id < 256) {
        const int bx = id & 7, by = id >> 3;
        gemm_body<4, true, false, false, true>(
            As, Bs, hidden, nullptr, ebf, 0, 0, nullptr,
            BSZ, HEADW, HDIM, bias2002, out, 0ll, HEADW,
            by * 256, bx * 256);
        return;
    }
    id -= 256;
    if (id < 4 * 103) {
        const int bx = id & 3, by = id >> 2;
        const int M = N0MAX + *n0p;
        const int m0 = by * 256;
        if (m0 >= M) return;
        gemm_body<4, true, true, true, false>(
            As, Bs, embed, hidden, d0bf, N0MAX, CUT0, idx0,
            M, HDIM, HDIM, nullptr, c0, 0ll, HDIM, m0, bx * 256);
        return;
    }
    id -= 412;
    const int M = N1MAX + *n1p;
    const int m0 = id * 256;
    if (m0 >= M) return;
    gemm_body<4, true, true, true, false>(
        As, Bs, embed, hidden, d1bf, N1MAX, CUT1, idx1,
        M, 256, HDIM, nullptr, c1, 0ll, 256, m0, 0);
}

// ---------------------------------------------------------------------------
// gemm_out01: out0 + out1 merged (role by bx<71).  Grid dim3(189, 32).
//   out0 = h0 @ e0^T + bias0  [n0 x 18000] fp32 at out + BSZ*HEADW
//   out1 = h1 @ e1^T + bias1  [n1 x 30000] fp32 after out0
// R9: RING=2 -> 64 KiB LDS -> 2 blocks/CU (16 waves): one block's fp32-store
// epilogue overlaps the other's K-loop; doubles latency-hiding TLP.
// __launch_bounds__(512,4): 4 waves/SIMD co-residency, caps VGPR at 128
// (current 96). x-fast dispatch interleaves the write-bound/MFMA-bound roles.
// ---------------------------------------------------------------------------
__global__ __launch_bounds__(512, 4) void gemm_out01(
    const unsigned short* __restrict__ c0, const unsigned short* __restrict__ c1,
    const int* __restrict__ n0p, const int* __restrict__ n1p,
    const float* __restrict__ bias0, const float* __restrict__ bias1,
    float* __restrict__ out)
{
    __shared__ unsigned short As[2][8192];
    __shared__ unsigned short Bs[2][8192];
    int bx = blockIdx.x;
    const unsigned short *A, *B; const float* bias;
    int M, N, K, ldC; long long cbase;
    if (bx < 71) {
        A = c0 + (size_t)N0MAX * HDIM; B = c0; bias = bias0;
        M = *n0p; N = N0MAX; K = HDIM; ldC = N0MAX;
        cbase = (long long)BSZ * HEADW;
    } else {
        bx -= 71;
        A = c1 + (size_t)N1MAX * 256; B = c1; bias = bias1;
        M = *n1p; N = N1MAX; K = 256; ldC = N1MAX;
        cbase = (long long)BSZ * HEADW + (long long)(*n0p) * N0MAX;
    }
    const int m0 = (int)blockIdx.y * 256;
    const int n0 = bx * 256;
    if (m0 >= M) return;
    gemm_body<2, false, false, false, true>(
        As, Bs, A, nullptr, B, 0, 0, nullptr,
        M, N, K, bias, out, cbase, ldC, m0, n0);
}

// ---------------------------------------------------------------------------
extern "C" void kernel_launch(void* const* d_in, const int* in_sizes, int n_in,
                              void* d_out, int out_size, void* d_ws, size_t ws_size,
                              hipStream_t stream) {
    (void)in_sizes; (void)n_in; (void)out_size; (void)ws_size;
    const float* hidden  = (const float*)d_in[0];
    const float* embed   = (const float*)d_in[1];
    const float* tailW   = (const float*)d_in[2];
    const float* tailb   = (const float*)d_in[3];
    const float* slbias  = (const float*)d_in[4];
    const float* bias0   = (const float*)d_in[5];
    const float* bias1   = (const float*)d_in[6];
    const float* down0   = (const float*)d_in[7];
    const float* down1   = (const float*)d_in[8];
    const int*   targets = (const int*)d_in[9];
    float* out = (float*)d_out;

    // workspace layout (~80 MB)
    char* ws = (char*)d_ws;
    int* n0p  = (int*)ws;
    int* n1p  = n0p + 1;
    int* idx0 = (int*)(ws + 256);
    int* idx1 = idx0 + BSZ;
    size_t off = 256 + 2 * (size_t)BSZ * 4;                                     // 65,792
    unsigned short* ebf  = (unsigned short*)(ws + off); off += (size_t)HEADW * HDIM * 2;  // 4.1 MB
    float* bias2002      = (float*)(ws + off);          off += 2048 * 4;                  // 8 KB
    // c0: [e0 (18000 rows); h0 (<=8192 rows)] bf16, ld 1024
    unsigned short* c0   = (unsigned short*)(ws + off);
    off += (size_t)(N0MAX + BSZ) * HDIM * 2;                                    // 53.6 MB
    // c1: [e1 (30000 rows); h1 (<=8192 rows)] bf16, ld 256
    unsigned short* c1   = (unsigned short*)(ws + off);
    off += (size_t)(N1MAX + BSZ) * 256 * 2;                                     // 19.6 MB
    unsigned short* d0bf = (unsigned short*)(ws + off); off += (size_t)HDIM * HDIM * 2;
    unsigned short* d1bf = (unsigned short*)(ws + off); off += (size_t)256 * HDIM * 2;

    // 1) all converts + bias concat + index build, one launch
    cvt_all<<<CVT_NBLK, 256, 0, stream>>>(
        embed, tailW, down0, down1, slbias, tailb, targets,
        ebf, d0bf, d1bf, bias2002, n0p, n1p, idx0, idx1);

    // 2) head + c0 + c1 merged
    gemm_mid<<<818, 512, 0, stream>>>(
        hidden, embed, ebf, d0bf, d1bf, bias2002,
        idx0, idx1, n0p, n1p, out, c0, c1);

    // 3) out0 + out1 merged (ring-2, 2 blocks/CU)
    gemm_out01<<<dim3(189, 32), 512, 0, stream>>>(
        c0, c1, n0p, n1p, bias0, bias1, out);
}

// Round 10
// 1560.122 us; speedup vs baseline: 2.0371x; 2.0371x over previous
//
#include <hip/hip_runtime.h>
#include <hip/hip_bf16.h>

// Problem constants
#define CUT0 2000
#define CUT1 20000
#define CUT2 50000
#define BSZ  8192
#define HDIM 1024
#define N0MAX 18000   // CUT1-CUT0
#define N1MAX 30000   // CUT2-CUT1
#define HEADW 2002    // CUT0 + 2 tail cols

typedef __attribute__((ext_vector_type(8))) short bf16x8;
typedef __attribute__((ext_vector_type(4))) float f32x4;
typedef __attribute__((ext_vector_type(4))) unsigned short us4;

__device__ __forceinline__ unsigned short f2bf(float x) {
    // round-to-nearest-even bf16
    unsigned u = __float_as_uint(x);
    unsigned r = u + 0x7fffu + ((u >> 16) & 1u);
    return (unsigned short)(r >> 16);
}

__device__ __forceinline__ bf16x8 pack8(f32x4 a, f32x4 b) {
    bf16x8 w;
    w[0] = (short)f2bf(a[0]); w[1] = (short)f2bf(a[1]);
    w[2] = (short)f2bf(a[2]); w[3] = (short)f2bf(a[3]);
    w[4] = (short)f2bf(b[0]); w[5] = (short)f2bf(b[1]);
    w[6] = (short)f2bf(b[2]); w[7] = (short)f2bf(b[3]);
    return w;
}

typedef const __attribute__((address_space(1))) void* gas_ptr;
typedef __attribute__((address_space(3))) void* las_ptr;

__device__ __forceinline__ void load_lds16(const void* g, void* l) {
    // 16B per lane, LDS dest = wave-uniform base + lane*16 (m97 pattern)
    __builtin_amdgcn_global_load_lds((gas_ptr)g, (las_ptr)l, 16, 0, 0);
}

// ---------------------------------------------------------------------------
// cvt_all: one launch doing every fp32->bf16 convert + bias concat + the
// cluster-index build. Segmented by blockIdx (2048 elems/block for cvt):
//   [0,1000)      embed[0:2000] -> ebf rows 0..1999
//   1000          tailW (2x1024) -> ebf rows 2000..2001
//   [1001,1513)   down0 -> d0bf
//   [1513,1641)   down1 -> d1bf
//   1641          bias2002 = [slbias; tailb] (fp32 copy)
//   1642          build_idx: idx0 (2000<=t<20000), idx1 (t>=20000), counts.
// ---------------------------------------------------------------------------
#define CVT_NBLK 1643
__global__ __launch_bounds__(256) void cvt_all(
    const float* __restrict__ embed,  const float* __restrict__ tailW,
    const float* __restrict__ down0,  const float* __restrict__ down1,
    const float* __restrict__ slbias, const float* __restrict__ tailb,
    const int* __restrict__ targets,
    unsigned short* __restrict__ ebf,
    unsigned short* __restrict__ d0bf, unsigned short* __restrict__ d1bf,
    float* __restrict__ bias2002,
    int* __restrict__ n0p, int* __restrict__ n1p,
    int* __restrict__ idx0, int* __restrict__ idx1)
{
    const int b = blockIdx.x;
    if (b == 1642) {
        // ---- build_idx ----
        __shared__ int s0[256], s1[256];
        const int t = threadIdx.x;
        const int base = t * 32;
        int tg[32];
        int c0n = 0, c1n = 0;
#pragma unroll
        for (int i = 0; i < 32; ++i) {
            tg[i] = targets[base + i];
            c0n += (tg[i] >= CUT0 && tg[i] < CUT1) ? 1 : 0;
            c1n += (tg[i] >= CUT1) ? 1 : 0;
        }
        s0[t] = c0n; s1[t] = c1n;
        __syncthreads();
        for (int o = 1; o < 256; o <<= 1) {
            int v0 = 0, v1 = 0;
            if (t >= o) { v0 = s0[t - o]; v1 = s1[t - o]; }
            __syncthreads();
            s0[t] += v0; s1[t] += v1;
            __syncthreads();
        }
        int p0 = s0[t] - c0n, p1 = s1[t] - c1n;   // exclusive prefix
#pragma unroll
        for (int i = 0; i < 32; ++i) {
            if (tg[i] >= CUT0 && tg[i] < CUT1)      idx0[p0++] = base + i;
            else if (tg[i] >= CUT1)                 idx1[p1++] = base + i;
        }
        if (t == 255) { *n0p = s0[255]; *n1p = s1[255]; }
        return;
    }
    if (b == 1641) {
        for (int j = threadIdx.x; j < HEADW; j += 256)
            bias2002[j] = (j < CUT0) ? slbias[j] : tailb[j - CUT0];
        return;
    }
    const float* src; unsigned short* dst; long long e;
    if (b < 1000)      { src = embed; dst = ebf;  e = (long long)b * 2048; }
    else if (b == 1000){ src = tailW; dst = ebf + (size_t)CUT0 * HDIM; e = 0; }
    else if (b < 1513) { src = down0; dst = d0bf; e = (long long)(b - 1001) * 2048; }
    else               { src = down1; dst = d1bf; e = (long long)(b - 1513) * 2048; }
    const long long i = e + (long long)threadIdx.x * 8;
    f32x4 a = *(const f32x4*)(src + i);
    f32x4 c = *(const f32x4*)(src + i + 4);
    us4 p = { f2bf(a[0]), f2bf(a[1]), f2bf(a[2]), f2bf(a[3]) };
    us4 q = { f2bf(c[0]), f2bf(c[1]), f2bf(c[2]), f2bf(c[3]) };
    *(us4*)(dst + i)     = p;
    *(us4*)(dst + i + 4) = q;
}

// ---------------------------------------------------------------------------
// gemm_body: C[m,n] = sum_k A[m,k]*B[n,k] (+bias[n]).  (R4..R8-verified core.)
//   256x256 tile, BK=32, 512 threads = 8 waves (2M x 4N), 128x64 per wave.
//   RING-slot LDS ring, RING-1 tiles prefetched, counted vmcnt = 4*infl,
//   raw s_barrier, T5 setprio.
//   R9 LESSON (spill cliff): this tile shape needs ~160 regs/wave
//   (acc[8][4]=128 + addressing; VGPR+AGPR unified on gfx950). Any
//   __launch_bounds__ min-waves >=4 caps at 128 and SPILLS THE ACCUMULATOR
//   to scratch (R9: 10.85 GB HBM/dispatch, 2150us). 2 blocks/CU is
//   structurally impossible at 256x256 -- run 1 block/CU, ring-4.
//   Bank swizzle: rows are 64B so the involution is slot ^ ((row>>1)&3),
//   applied on gload_lds SOURCE pre-swizzle, A_F32 ds_write, and ds_read
//   (rule #21: both-sides-or-neither).
//   A_F32: A read fp32 (main=Av via gbase, gather=AgF via idxTail),
//   in-register cvt, T14 split; A-reg loads issued BEFORE issueB (R8:
//   keeps implicit ds_write wait at vmcnt(2), not 0).
//   Rows clamped to M-1/N-1 (don't-care values, epilogue guards).
//   LDS is DECLARED BY THE CALLER and passed in (R6 lesson: hipcc SUMS
//   function-scope __shared__ across inlined template instantiations).
//   (R3 lesson: do NOT 1D/XCD-swizzle grids that early-exit on device M.)
//   (R8 lesson: do NOT permute role-merged grids -- scatters L2 panel reuse.)
// ---------------------------------------------------------------------------
template<int RING, bool A_F32, bool SPLIT_GATHER, bool OUT_BF16, bool HAS_BIAS>
__device__ __forceinline__ void gemm_body(
    unsigned short (* __restrict__ As)[8192],   // [RING][8192] caller LDS
    unsigned short (* __restrict__ Bs)[8192],   // [RING][8192] caller LDS
    const void* __restrict__ Av, const float* __restrict__ AgF,
    const unsigned short* __restrict__ B,
    int gsplit, int gbase, const int* __restrict__ idxTail,
    int M, int N, int K,
    const float* __restrict__ bias,
    void* __restrict__ Cv, long long cbase, int ldC,
    int m0, int n0)
{
    static_assert(RING == 2 || RING == 4, "ring size");
    constexpr int PF = RING - 1;          // tiles prefetched ahead
    constexpr int SMSK = RING - 1;        // slot mask

    const int tid  = threadIdx.x;
    const int wave = tid >> 6, lane = tid & 63;
    const int wr = wave >> 2;        // 0..1  (M)
    const int wc = wave & 3;         // 0..3  (N)
    const int lrow = lane & 15;
    const int quad = lane >> 4;

    // ---- B staging (gload_lds, pre-swizzled global source; rule #21)
    const int srow = lane >> 2;                                  // 0..15
    const int scol = (((lane & 3) ^ ((srow >> 1) & 3)) << 3);    // elems
    int tr0 = wave * 32 + srow, tr1 = tr0 + 16;
    int bn0 = n0 + tr0; bn0 = bn0 < N ? bn0 : N - 1;
    int bn1 = n0 + tr1; bn1 = bn1 < N ? bn1 : N - 1;
    const unsigned short* bP0 = B + (long long)bn0 * K + scol;
    const unsigned short* bP1 = B + (long long)bn1 * K + scol;

    // ---- A staging setup
    const unsigned short* aP0 = nullptr;
    const unsigned short* aP1 = nullptr;
    const float* aF = nullptr;
    int oA0 = 0, oA1 = 0, sA0 = 0, sA1 = 0;
    if constexpr (!A_F32) {
        int am0 = m0 + tr0; am0 = am0 < M ? am0 : M - 1;
        int am1 = m0 + tr1; am1 = am1 < M ? am1 : M - 1;
        long long ar0, ar1;
        if constexpr (SPLIT_GATHER) {
            ar0 = (am0 < gsplit) ? (long long)(gbase + am0) : (long long)idxTail[am0 - gsplit];
            ar1 = (am1 < gsplit) ? (long long)(gbase + am1) : (long long)idxTail[am1 - gsplit];
        } else { ar0 = am0; ar1 = am1; }
        const unsigned short* Ab = (const unsigned short*)Av;
        aP0 = Ab + ar0 * (long long)K + scol;
        aP1 = Ab + ar1 * (long long)K + scol;
    } else {
        // lane l -> row rA=l>>1 (2 lanes/row); slots sA0=l&1, sA1=2+(l&1);
        // write at LDS col (s ^ ((rA>>1)&3)): enumerated 2-way max (free)
        const int rA  = lane >> 1;                // 0..31
        const int trA = wave * 32 + rA;           // LDS row 0..255
        int amF = m0 + trA; amF = amF < M ? amF : M - 1;
        long long rowi; const float* bp;
        if constexpr (SPLIT_GATHER) {
            if (amF < gsplit) { rowi = (long long)(gbase + amF); bp = (const float*)Av; }
            else              { rowi = (long long)idxTail[amF - gsplit]; bp = AgF; }
        } else { rowi = amF; bp = (const float*)Av; }
        aF  = bp + rowi * (long long)K;
        sA0 = (lane & 1);
        sA1 = 2 + (lane & 1);
        const int xA = (rA >> 1) & 3;
        oA0 = trA * 32 + ((sA0 ^ xA) << 3);
        oA1 = trA * 32 + ((sA1 ^ xA) << 3);
    }

    f32x4 acc[8][4];
#pragma unroll
    for (int i = 0; i < 8; ++i)
#pragma unroll
        for (int j = 0; j < 4; ++j) acc[i][j] = (f32x4){0.f, 0.f, 0.f, 0.f};

    const int KT = K >> 5;   // BK = 32

    auto issueB = [&](int tt) {
        unsigned short* bs = &Bs[tt & SMSK][wave * 1024];
        load_lds16(bP0 + (tt << 5), bs);
        load_lds16(bP1 + (tt << 5), bs + 512);
    };
    auto issueA16 = [&](int tt) {
        unsigned short* as = &As[tt & SMSK][wave * 1024];
        load_lds16(aP0 + (tt << 5), as);
        load_lds16(aP1 + (tt << 5), as + 512);
    };

    // prologue: PF tiles in flight (A_F32: A staged immediately, B via ring)
    const int npro = KT < PF ? KT : PF;
    for (int tt = 0; tt < npro; ++tt) {
        if constexpr (!A_F32) {
            issueB(tt);
            issueA16(tt);
        } else {
            const float* p = aF + (tt << 5);
            f32x4 x0 = *(const f32x4*)(p + sA0 * 8);
            f32x4 x1 = *(const f32x4*)(p + sA0 * 8 + 4);
            f32x4 y0 = *(const f32x4*)(p + sA1 * 8);
            f32x4 y1 = *(const f32x4*)(p + sA1 * 8 + 4);
            issueB(tt);                      // B newer than A-regs (R8)
            *(bf16x8*)&As[tt & SMSK][oA0] = pack8(x0, x1);
            *(bf16x8*)&As[tt & SMSK][oA1] = pack8(y0, y1);
        }
    }
    if constexpr (A_F32)
        asm volatile("s_waitcnt lgkmcnt(0)" ::: "memory");

    // read swizzle: global slot quad lives at LDS slot quad^((R>>1)&3);
    // (R>>1)&3 == (lrow>>1)&3 (R = 16*sub + lrow). Per-lane constant.
    const int rdswz = ((quad ^ ((lrow >> 1) & 3)) << 3);     // elems

    for (int t = 0; t < KT; ++t) {
        const int tt = t + PF;
        const bool pf = (tt < KT);

        f32x4 x0, x1, y0, y1;                    // A_F32 in-flight A regs (T14)
        if constexpr (!A_F32) {
            if (pf) { issueB(tt); issueA16(tt); }
        } else {
            if (pf) {
                // A-regs FIRST (older queue slots), then B (R8): the
                // post-MFMA ds_write's implicit wait is then vmcnt(2), not 0.
                const float* p = aF + (tt << 5);
                x0 = *(const f32x4*)(p + sA0 * 8);
                x1 = *(const f32x4*)(p + sA0 * 8 + 4);
                y0 = *(const f32x4*)(p + sA1 * 8);
                y1 = *(const f32x4*)(p + sA1 * 8 + 4);
                issueB(tt);
            }
        }

        int infl = KT - 1 - t; if (infl > PF) infl = PF;    // tiles beyond t in flight
        if constexpr (!A_F32) {
            // counted vmcnt = 4 * infl (4 gloads per in-flight tile)
            if (infl >= 3)      asm volatile("s_waitcnt vmcnt(12)" ::: "memory");
            else if (infl == 2) asm volatile("s_waitcnt vmcnt(8)"  ::: "memory");
            else if (infl == 1) asm volatile("s_waitcnt vmcnt(4)"  ::: "memory");
            else                asm volatile("s_waitcnt vmcnt(0)"  ::: "memory");
        } else {
            if (infl >= 3)      asm volatile("s_waitcnt vmcnt(8)"  ::: "memory");
            else if (infl == 2) asm volatile("s_waitcnt vmcnt(4)"  ::: "memory");
            else if (infl == 1) asm volatile("s_waitcnt vmcnt(2)"  ::: "memory");
            else                asm volatile("s_waitcnt vmcnt(0)"  ::: "memory");
        }

        __builtin_amdgcn_s_barrier();
        asm volatile("" ::: "memory");   // keep ds_reads below the barrier

        const unsigned short* Asl = &As[t & SMSK][0];
        const unsigned short* Bsl = &Bs[t & SMSK][0];

        bf16x8 a[8], b[4];
#pragma unroll
        for (int mi = 0; mi < 8; ++mi) {
            const int R = wr * 128 + mi * 16 + lrow;
            a[mi] = *(const bf16x8*)&Asl[R * 32 + rdswz];
        }
#pragma unroll
        for (int nj = 0; nj < 4; ++nj) {
            const int R = wc * 64 + nj * 16 + lrow;
            b[nj] = *(const bf16x8*)&Bsl[R * 32 + rdswz];
        }

        __builtin_amdgcn_s_setprio(1);
#pragma unroll
        for (int mi = 0; mi < 8; ++mi)
#pragma unroll
            for (int nj = 0; nj < 4; ++nj)
                acc[mi][nj] = __builtin_amdgcn_mfma_f32_16x16x32_bf16(
                    a[mi], b[nj], acc[mi][nj], 0, 0, 0);
        __builtin_amdgcn_s_setprio(0);

        if constexpr (A_F32) {
            // deferred cvt + swizzled ds_write for tile t+PF (slot freed at
            // end of iter t-1; readers wait >=2 barriers from here).
            if (pf) {
                *(bf16x8*)&As[tt & SMSK][oA0] = pack8(x0, x1);
                *(bf16x8*)&As[tt & SMSK][oA1] = pack8(y0, y1);
            }
            asm volatile("s_waitcnt lgkmcnt(0)" ::: "memory");
        }

        asm volatile("" ::: "memory");   // keep ds ops above the end barrier
        __builtin_amdgcn_s_barrier();    // slot t&SMSK free for tile t+RING
    }

    // epilogue: C/D layout col=lane&15, row=quad*4+reg  [m89/m91 verified]
#pragma unroll
    for (int mi = 0; mi < 8; ++mi) {
#pragma unroll
        for (int v = 0; v < 4; ++v) {
            int m = m0 + wr * 128 + mi * 16 + quad * 4 + v;
            if (m >= M) continue;
#pragma unroll
            for (int nj = 0; nj < 4; ++nj) {
                int n = n0 + wc * 64 + nj * 16 + lrow;
                if (n >= N) continue;
                float r = acc[mi][nj][v];
                if constexpr (OUT_BF16) {
                    ((unsigned short*)Cv)[(long long)m * ldC + n] = f2bf(r);
                } else {
                    if constexpr (HAS_BIAS) r += bias[n];
                    ((float*)Cv)[cbase + (long long)m * ldC + n] = r;
                }
            }
        }
    }
}

// ---------------------------------------------------------------------------
// gemm_mid: head + c0 + c1 in one launch (1D grid, 818 blocks, role by id).
//   [0,256)    head: out[:, 0:2002] = hidden @ [embed0;tailW]^T + bias2002
//   [256,668)  c0 = [embed[2000:20000]; hidden[idx0]] @ down0^T -> bf16
//   [668,818)  c1 = [embed[20000:50000]; hidden[idx1]] @ down1^T -> bf16
// Contiguous role slabs (R8 lesson: permuting ids scatters L2 panel reuse).
// Ring-4, single 128 KiB LDS slab shared by all instantiations (R6 fix).
// ---------------------------------------------------------------------------
__global__ __launch_bounds__(512) void gemm_mid(
    const float* __restrict__ hidden, const float* __restrict__ embed,
    const unsigned short* __restrict__ ebf,
    const unsigned short* __restrict__ d0bf, const unsigned short* __restrict__ d1bf,
    const float* __restrict__ bias2002,
    const int* __restrict__ idx0, const int* __restrict__ idx1,
    const int* __restrict__ n0p, const int* __restrict__ n1p,
    float* __restrict__ out,
    unsigned short* __restrict__ c0, unsigned short* __restrict__ c1)
{
    __shared__ unsigned short As[4][8192];
    __shared__ unsigned short Bs[4][8192];
    int id = blockIdx.x;
    if (id < 256) {
        const int bx = id & 7, by = id >> 3;
        gemm_body<4, true, false, false, true>(
            As, Bs, hidden, nullptr, ebf, 0, 0, nullptr,
            BSZ, HEADW, HDIM, bias2002, out, 0ll, HEADW,
            by * 256, bx * 256);
        return;
    }
    id -= 256;
    if (id < 4 * 103) {
        const int bx = id & 3, by = id >> 2;
        const int M = N0MAX + *n0p;
        const int m0 = by * 256;
        if (m0 >= M) return;
        gemm_body<4, true, true, true, false>(
            As, Bs, embed, hidden, d0bf, N0MAX, CUT0, idx0,
            M, HDIM, HDIM, nullptr, c0, 0ll, HDIM, m0, bx * 256);
        return;
    }
    id -= 412;
    const int M = N1MAX + *n1p;
    const int m0 = id * 256;
    if (m0 >= M) return;
    gemm_body<4, true, true, true, false>(
        As, Bs, embed, hidden, d1bf, N1MAX, CUT1, idx1,
        M, 256, HDIM, nullptr, c1, 0ll, 256, m0, 0);
}

// ---------------------------------------------------------------------------
// gemm_out01: out0 + out1 merged (role by bx<71).  Grid dim3(189, 32).
//   out0 = h0 @ e0^T + bias0  [n0 x 18000] fp32 at out + BSZ*HEADW
//   out1 = h1 @ e1^T + bias1  [n1 x 30000] fp32 after out0
// R10: reverted to the R7-verified config -- ring-4, 128 KiB LDS, plain
// __launch_bounds__(512). R9's (512,4) min-wave bound capped regs at 128
// (< the ~160 this tile needs) and spilled the accumulator (10.85 GB HBM
// traffic, 2150us). 1 block/CU is the correct operating point here.
// ---------------------------------------------------------------------------
__global__ __launch_bounds__(512) void gemm_out01(
    const unsigned short* __restrict__ c0, const unsigned short* __restrict__ c1,
    const int* __restrict__ n0p, const int* __restrict__ n1p,
    const float* __restrict__ bias0, const float* __restrict__ bias1,
    float* __restrict__ out)
{
    __shared__ unsigned short As[4][8192];
    __shared__ unsigned short Bs[4][8192];
    int bx = blockIdx.x;
    const unsigned short *A, *B; const float* bias;
    int M, N, K, ldC; long long cbase;
    if (bx < 71) {
        A = c0 + (size_t)N0MAX * HDIM; B = c0; bias = bias0;
        M = *n0p; N = N0MAX; K = HDIM; ldC = N0MAX;
        cbase = (long long)BSZ * HEADW;
    } else {
        bx -= 71;
        A = c1 + (size_t)N1MAX * 256; B = c1; bias = bias1;
        M = *n1p; N = N1MAX; K = 256; ldC = N1MAX;
        cbase = (long long)BSZ * HEADW + (long long)(*n0p) * N0MAX;
    }
    const int m0 = (int)blockIdx.y * 256;
    const int n0 = bx * 256;
    if (m0 >= M) return;
    gemm_body<4, false, false, false, true>(
        As, Bs, A, nullptr, B, 0, 0, nullptr,
        M, N, K, bias, out, cbase, ldC, m0, n0);
}

// ---------------------------------------------------------------------------
extern "C" void kernel_launch(void* const* d_in, const int* in_sizes, int n_in,
                              void* d_out, int out_size, void* d_ws, size_t ws_size,
                              hipStream_t stream) {
    (void)in_sizes; (void)n_in; (void)out_size; (void)ws_size;
    const float* hidden  = (const float*)d_in[0];
    const float* embed   = (const float*)d_in[1];
    const float* tailW   = (const float*)d_in[2];
    const float* tailb   = (const float*)d_in[3];
    const float* slbias  = (const float*)d_in[4];
    const float* bias0   = (const float*)d_in[5];
    const float* bias1   = (const float*)d_in[6];
    const float* down0   = (const float*)d_in[7];
    const float* down1   = (const float*)d_in[8];
    const int*   targets = (const int*)d_in[9];
    float* out = (float*)d_out;

    // workspace layout (~80 MB)
    char* ws = (char*)d_ws;
    int* n0p  = (int*)ws;
    int* n1p  = n0p + 1;
    int* idx0 = (int*)(ws + 256);
    int* idx1 = idx0 + BSZ;
    size_t off = 256 + 2 * (size_t)BSZ * 4;                                     // 65,792
    unsigned short* ebf  = (unsigned short*)(ws + off); off += (size_t)HEADW * HDIM * 2;  // 4.1 MB
    float* bias2002      = (float*)(ws + off);          off += 2048 * 4;                  // 8 KB
    // c0: [e0 (18000 rows); h0 (<=8192 rows)] bf16, ld 1024
    unsigned short* c0   = (unsigned short*)(ws + off);
    off += (size_t)(N0MAX + BSZ) * HDIM * 2;                                    // 53.6 MB
    // c1: [e1 (30000 rows); h1 (<=8192 rows)] bf16, ld 256
    unsigned short* c1   = (unsigned short*)(ws + off);
    off += (size_t)(N1MAX + BSZ) * 256 * 2;                                     // 19.6 MB
    unsigned short* d0bf = (unsigned short*)(ws + off); off += (size_t)HDIM * HDIM * 2;
    unsigned short* d1bf = (unsigned short*)(ws + off); off += (size_t)256 * HDIM * 2;

    // 1) all converts + bias concat + index build, one launch
    cvt_all<<<CVT_NBLK, 256, 0, stream>>>(
        embed, tailW, down0, down1, slbias, tailb, targets,
        ebf, d0bf, d1bf, bias2002, n0p, n1p, idx0, idx1);

    // 2) head + c0 + c1 merged
    gemm_mid<<<818, 512, 0, stream>>>(
        hidden, embed, ebf, d0bf, d1bf, bias2002,
        idx0, idx1, n0p, n1p, out, c0, c1);

    // 3) out0 + out1 merged (ring-4, 1 block/CU -- R9 spill lesson)
    gemm_out01<<<dim3(189, 32), 512, 0, stream>>>(
        c0, c1, n0p, n1p, bias0, bias1, out);
}